// Round 3
// baseline (167.195 us; speedup 1.0000x reference)
//
#include <hip/hip_runtime.h>

// x [B=16, N=1024, F=256] fp32.  Factored, 5 kernels:
//  K1 prep:  xb=bf16(x); W{a,b,u,r}b=bf16(W*); Wc=Wr@Wu (bf16), bc=Wr@bu
//  K2 proj4: {alpha,beta,unary,U2} = xb @ {Wa,Wb,Wu,Wc}^T (+bu/+bc), bf16;
//            dpart[bn][m] = partial alpha[m,:].beta[m,:] over this block's 64 cols
//  K3 tn:    Mpart[chunk][b] = beta[b,chunk]^T @ unary[b,chunk]  (M row-major, fp32)
//  K4 qt:    Qt[b][j][k] = sum_n Wr[j,n] * M[b][k,n]   (reduce Mpart in staging)
//  K5 final: out[m,j] = (alpha[m,:].Qt[j,:] - d[m]*U2[m,j])/N + x[m,j]  (fp32)

typedef __bf16 bf16;
typedef float floatx4 __attribute__((ext_vector_type(4)));
typedef bf16 bf16x8 __attribute__((ext_vector_type(8)));
typedef bf16 bf16x4 __attribute__((ext_vector_type(4)));

constexpr int FD = 256;
constexpr int NB = 16;
constexpr int NN = 1024;
constexpr int RR = NB * NN;   // 16384

// ---------------- K1: prep ----------------
// grid: [0,2048) cvt_x | [2048,2080) cvt W | [2080,2144) Wc | 2144 bc
__global__ __launch_bounds__(256)
void prep(const float* __restrict__ x, const float* __restrict__ Wa, const float* __restrict__ Wb,
          const float* __restrict__ Wu, const float* __restrict__ bu, const float* __restrict__ Wr,
          bf16* __restrict__ xb, bf16* __restrict__ Wab, bf16* __restrict__ Wbb,
          bf16* __restrict__ Wub, bf16* __restrict__ Wrb, bf16* __restrict__ Wcb,
          float* __restrict__ bc)
{
    const int blk = blockIdx.x, tid = threadIdx.x;
    if (blk < 2048) {  // cvt x: 8 elems/thread
        size_t i = ((size_t)blk * 256 + tid) * 8;
        float4 v0 = *(const float4*)&x[i];
        float4 v1 = *(const float4*)&x[i + 4];
        bf16x8 o = { (bf16)v0.x, (bf16)v0.y, (bf16)v0.z, (bf16)v0.w,
                     (bf16)v1.x, (bf16)v1.y, (bf16)v1.z, (bf16)v1.w };
        *(bf16x8*)&xb[i] = o;
    } else if (blk < 2080) {  // cvt weights: 4 weights x 8 blocks
        int rel = blk - 2048, w = rel >> 3, wb = rel & 7;
        const float* src = (w == 0) ? Wa : (w == 1) ? Wb : (w == 2) ? Wu : Wr;
        bf16* dst = (w == 0) ? Wab : (w == 1) ? Wbb : (w == 2) ? Wub : Wrb;
        for (int it = 0; it < 8; it++) {
            int i = wb * 8192 + it * 1024 + tid * 4;
            float4 v = *(const float4*)&src[i];
            bf16x4 o = { (bf16)v.x, (bf16)v.y, (bf16)v.z, (bf16)v.w };
            *(bf16x4*)&dst[i] = o;
        }
    } else if (blk < 2144) {  // Wc[j][f] = sum_g Wr[j][g]*Wu[g][f], 4 rows/block
        int j0 = (blk - 2080) * 4;
        float acc[4] = {};
        for (int g = 0; g < FD; g++) {
            float wu = Wu[g * FD + tid];
            #pragma unroll
            for (int jr = 0; jr < 4; jr++)
                acc[jr] += Wr[(j0 + jr) * FD + g] * wu;
        }
        #pragma unroll
        for (int jr = 0; jr < 4; jr++)
            Wcb[(j0 + jr) * FD + tid] = (bf16)acc[jr];
    } else {  // bc[j] = Wr[j,:].bu
        float s = 0.0f;
        for (int g = 0; g < FD; g++) s += Wr[tid * FD + g] * bu[g];
        bc[tid] = s;
    }
}

// ---------------- K2: fused 4-way projection + diag partials ----------------
__global__ __launch_bounds__(256)
void proj4(const bf16* __restrict__ A,
           const bf16* __restrict__ W0, const bf16* __restrict__ W1,
           const bf16* __restrict__ W2, const bf16* __restrict__ W3,
           bf16* __restrict__ O0, bf16* __restrict__ O1, bf16* __restrict__ O2, bf16* __restrict__ O3,
           const float* __restrict__ bu, const float* __restrict__ bc,
           float* __restrict__ dpart)
{
    constexpr int BM = 128, BN = 64, BK = 32, LDK = 40;
    __shared__ bf16 As[BM][LDK];
    __shared__ bf16 Bs[4][BN][LDK];
    const int tid = threadIdx.x;
    const int wave = tid >> 6, lane = tid & 63;
    const int q = lane >> 4, l16 = lane & 15;
    const int bm = blockIdx.y * BM, bn = blockIdx.x * BN;
    const bf16* Wp[4] = { W0, W1, W2, W3 };

    floatx4 acc[4][2][4] = {};

    for (int k0 = 0; k0 < FD; k0 += BK) {
        {
            int c = tid, row = c >> 2, k8 = (c & 3) * 8;
            *(int4*)&As[row][k8] = *(const int4*)&A[(size_t)(bm + row) * FD + k0 + k8];
            c = tid + 256; row = c >> 2; k8 = (c & 3) * 8;
            *(int4*)&As[row][k8] = *(const int4*)&A[(size_t)(bm + row) * FD + k0 + k8];
        }
        #pragma unroll
        for (int w = 0; w < 4; w++) {
            int row = tid >> 2, k8 = (tid & 3) * 8;
            *(int4*)&Bs[w][row][k8] = *(const int4*)&Wp[w][(size_t)(bn + row) * FD + k0 + k8];
        }
        __syncthreads();
        bf16x8 af[2];
        #pragma unroll
        for (int mi = 0; mi < 2; mi++)
            af[mi] = *(const bf16x8*)&As[wave * 32 + mi * 16 + l16][q * 8];
        #pragma unroll
        for (int w = 0; w < 4; w++) {
            bf16x8 bq[4];
            #pragma unroll
            for (int nj = 0; nj < 4; nj++)
                bq[nj] = *(const bf16x8*)&Bs[w][nj * 16 + l16][q * 8];
            #pragma unroll
            for (int mi = 0; mi < 2; mi++)
                #pragma unroll
                for (int nj = 0; nj < 4; nj++)
                    acc[w][mi][nj] = __builtin_amdgcn_mfma_f32_16x16x32_bf16(af[mi], bq[nj], acc[w][mi][nj], 0, 0, 0);
        }
        __syncthreads();
    }

    bf16* Op[4] = { O0, O1, O2, O3 };
    #pragma unroll
    for (int w = 0; w < 4; w++) {
        #pragma unroll
        for (int mi = 0; mi < 2; mi++)
            #pragma unroll
            for (int i = 0; i < 4; i++) {
                int m = bm + wave * 32 + mi * 16 + q * 4 + i;
                #pragma unroll
                for (int nj = 0; nj < 4; nj++) {
                    int n = bn + nj * 16 + l16;
                    float v = acc[w][mi][nj][i];
                    if (w == 2) v += bu[n];
                    if (w == 3) v += bc[n];
                    Op[w][(size_t)m * FD + n] = (bf16)v;
                }
            }
    }

    // diag partials: dpart[blockIdx.x][m] = sum over this block's 64 cols of alpha*beta
    #pragma unroll
    for (int mi = 0; mi < 2; mi++)
        #pragma unroll
        for (int i = 0; i < 4; i++) {
            float p = 0.0f;
            #pragma unroll
            for (int nj = 0; nj < 4; nj++)
                p += acc[0][mi][nj][i] * acc[1][mi][nj][i];
            #pragma unroll
            for (int off = 1; off < 16; off <<= 1) p += __shfl_xor(p, off);
            if (l16 == 0) {
                int m = bm + wave * 32 + mi * 16 + q * 4 + i;
                dpart[(size_t)blockIdx.x * RR + m] = p;
            }
        }
}

// ---------------- K3: TN split-K: Mpart[chunk][b][g][f] = sum_n beta[n,g]*unary[n,f] ----------------
__global__ __launch_bounds__(256)
void gemm_tn_mfma(const bf16* __restrict__ Aall, const bf16* __restrict__ Ball, float* __restrict__ Mpart)
{
    constexpr int BG = 64, BF = 64, BK = 32, LDK = 40, CHUNK = 256;
    __shared__ bf16 Ags[BG][LDK];
    __shared__ bf16 Bfs[BF][LDK];
    const int tid = threadIdx.x;
    const int wave = tid >> 6, lane = tid & 63;
    const int q = lane >> 4, l16 = lane & 15;
    const int b = blockIdx.z >> 2, chunk = blockIdx.z & 3;
    const int bg = blockIdx.y * BG, bfo = blockIdx.x * BF;
    const bf16* Ab = Aall + (size_t)b * NN * FD;
    const bf16* Bb = Ball + (size_t)b * NN * FD;

    floatx4 acc[4] = {};
    const int n0base = chunk * CHUNK;
    for (int nc = 0; nc < CHUNK; nc += BK) {
        int nr = tid >> 3, g8 = (tid & 7) * 8;
        bf16x8 va = *(const bf16x8*)&Ab[(size_t)(n0base + nc + nr) * FD + bg + g8];
        bf16x8 vb = *(const bf16x8*)&Bb[(size_t)(n0base + nc + nr) * FD + bfo + g8];
        #pragma unroll
        for (int j = 0; j < 8; j++) {
            Ags[g8 + j][nr] = va[j];
            Bfs[g8 + j][nr] = vb[j];
        }
        __syncthreads();
        bf16x8 af = *(const bf16x8*)&Ags[wave * 16 + l16][q * 8];
        #pragma unroll
        for (int fj = 0; fj < 4; fj++) {
            bf16x8 bq = *(const bf16x8*)&Bfs[fj * 16 + l16][q * 8];
            acc[fj] = __builtin_amdgcn_mfma_f32_16x16x32_bf16(af, bq, acc[fj], 0, 0, 0);
        }
        __syncthreads();
    }
    float* P = Mpart + (size_t)chunk * (NB * FD * FD) + (size_t)b * FD * FD;
    #pragma unroll
    for (int i = 0; i < 4; i++) {
        int g = bg + wave * 16 + q * 4 + i;
        #pragma unroll
        for (int fj = 0; fj < 4; fj++)
            P[(size_t)g * FD + bfo + fj * 16 + l16] = acc[fj][i];
    }
}

// ---------------- K4: Qt[b][j][k] = sum_n Wr[j,n] * M[b][k,n], M = sum_c Mpart[c] ----------------
__global__ __launch_bounds__(256)
void qt_mfma(const bf16* __restrict__ Wrb, const float* __restrict__ Mpart, bf16* __restrict__ Qt)
{
    constexpr int BJ = 64, BKT = 64, BK = 32, LDK = 40;
    __shared__ bf16 As[BJ][LDK];   // Wr rows j
    __shared__ bf16 Bs[BKT][LDK];  // M rows k (reduced, bf16)
    const int tid = threadIdx.x;
    const int wave = tid >> 6, lane = tid & 63;
    const int q = lane >> 4, l16 = lane & 15;
    const int b = blockIdx.z;
    const int bj = blockIdx.y * BJ, bk = blockIdx.x * BKT;
    const size_t S = (size_t)NB * FD * FD;
    const float* Mb = Mpart + (size_t)b * FD * FD;

    floatx4 acc[4] = {};
    for (int n0 = 0; n0 < FD; n0 += BK) {
        int row = tid >> 2, n8 = (tid & 3) * 8;
        *(int4*)&As[row][n8] = *(const int4*)&Wrb[(size_t)(bj + row) * FD + n0 + n8];
        // B: reduce 4 fp32 chunks -> bf16
        const float* base = &Mb[(size_t)(bk + row) * FD + n0 + n8];
        float4 s0 = *(const float4*)&base[0]       , s1 = *(const float4*)&base[4];
        float4 t0 = *(const float4*)&base[S]       , t1 = *(const float4*)&base[S + 4];
        float4 u0 = *(const float4*)&base[2 * S]   , u1 = *(const float4*)&base[2 * S + 4];
        float4 v0 = *(const float4*)&base[3 * S]   , v1 = *(const float4*)&base[3 * S + 4];
        bf16x8 o = { (bf16)(s0.x + t0.x + u0.x + v0.x), (bf16)(s0.y + t0.y + u0.y + v0.y),
                     (bf16)(s0.z + t0.z + u0.z + v0.z), (bf16)(s0.w + t0.w + u0.w + v0.w),
                     (bf16)(s1.x + t1.x + u1.x + v1.x), (bf16)(s1.y + t1.y + u1.y + v1.y),
                     (bf16)(s1.z + t1.z + u1.z + v1.z), (bf16)(s1.w + t1.w + u1.w + v1.w) };
        *(bf16x8*)&Bs[row][n8] = o;
        __syncthreads();
        bf16x8 af = *(const bf16x8*)&As[wave * 16 + l16][q * 8];
        #pragma unroll
        for (int kj = 0; kj < 4; kj++) {
            bf16x8 bq = *(const bf16x8*)&Bs[kj * 16 + l16][q * 8];
            acc[kj] = __builtin_amdgcn_mfma_f32_16x16x32_bf16(af, bq, acc[kj], 0, 0, 0);
        }
        __syncthreads();
    }
    bf16* Qb = Qt + (size_t)b * FD * FD;
    #pragma unroll
    for (int i = 0; i < 4; i++) {
        int j = bj + wave * 16 + q * 4 + i;
        #pragma unroll
        for (int kj = 0; kj < 4; kj++)
            Qb[(size_t)j * FD + bk + kj * 16 + l16] = (bf16)acc[kj][i];
    }
}

// ---------------- K5: out = (alpha @ Qt[b]^T(NT) - d*U2)/N + x ----------------
__global__ __launch_bounds__(256)
void final_mfma(const bf16* __restrict__ alpha, const bf16* __restrict__ Qt,
                const float* __restrict__ dpart, const bf16* __restrict__ U2,
                const float* __restrict__ x, float* __restrict__ out)
{
    constexpr int BM = 128, BN = 64, BK = 32, LDK = 40;
    __shared__ bf16 As[BM][LDK];
    __shared__ bf16 Bs[BN][LDK];
    const int tid = threadIdx.x;
    const int wave = tid >> 6, lane = tid & 63;
    const int q = lane >> 4, l16 = lane & 15;
    const int bm = blockIdx.y * BM, bn = blockIdx.x * BN;
    const bf16* Qb = Qt + (size_t)(bm >> 10) * FD * FD;

    floatx4 acc[2][4] = {};
    for (int k0 = 0; k0 < FD; k0 += BK) {
        int c = tid, row = c >> 2, k8 = (c & 3) * 8;
        *(int4*)&As[row][k8] = *(const int4*)&alpha[(size_t)(bm + row) * FD + k0 + k8];
        c = tid + 256; row = c >> 2; k8 = (c & 3) * 8;
        *(int4*)&As[row][k8] = *(const int4*)&alpha[(size_t)(bm + row) * FD + k0 + k8];
        int rb = tid >> 2, kb8 = (tid & 3) * 8;
        *(int4*)&Bs[rb][kb8] = *(const int4*)&Qb[(size_t)(bn + rb) * FD + k0 + kb8];
        __syncthreads();
        bf16x8 af[2], bq[4];
        #pragma unroll
        for (int mi = 0; mi < 2; mi++)
            af[mi] = *(const bf16x8*)&As[wave * 32 + mi * 16 + l16][q * 8];
        #pragma unroll
        for (int nj = 0; nj < 4; nj++)
            bq[nj] = *(const bf16x8*)&Bs[nj * 16 + l16][q * 8];
        #pragma unroll
        for (int mi = 0; mi < 2; mi++)
            #pragma unroll
            for (int nj = 0; nj < 4; nj++)
                acc[mi][nj] = __builtin_amdgcn_mfma_f32_16x16x32_bf16(af[mi], bq[nj], acc[mi][nj], 0, 0, 0);
        __syncthreads();
    }

    #pragma unroll
    for (int mi = 0; mi < 2; mi++)
        #pragma unroll
        for (int i = 0; i < 4; i++) {
            int m = bm + wave * 32 + mi * 16 + q * 4 + i;
            float d = dpart[m] + dpart[RR + m] + dpart[2 * RR + m] + dpart[3 * RR + m];
            #pragma unroll
            for (int nj = 0; nj < 4; nj++) {
                int n = bn + nj * 16 + l16;
                float v = (acc[mi][nj][i] - d * (float)U2[(size_t)m * FD + n]) * (1.0f / 1024.0f);
                out[(size_t)m * FD + n] = v + x[(size_t)m * FD + n];
            }
        }
}

extern "C" void kernel_launch(void* const* d_in, const int* in_sizes, int n_in,
                              void* d_out, int out_size, void* d_ws, size_t ws_size,
                              hipStream_t stream)
{
    const float* x  = (const float*)d_in[0];
    const float* Wa = (const float*)d_in[1];
    const float* Wb = (const float*)d_in[2];
    const float* Wu = (const float*)d_in[3];
    const float* bu = (const float*)d_in[4];
    const float* Wr = (const float*)d_in[5];
    float* out = (float*)d_out;

    char* w = (char*)d_ws;
    bf16* xb    = (bf16*)w;  w += (size_t)RR * FD * 2;
    bf16* Wab   = (bf16*)w;  w += (size_t)FD * FD * 2;
    bf16* Wbb   = (bf16*)w;  w += (size_t)FD * FD * 2;
    bf16* Wub   = (bf16*)w;  w += (size_t)FD * FD * 2;
    bf16* Wrb   = (bf16*)w;  w += (size_t)FD * FD * 2;
    bf16* Wcb   = (bf16*)w;  w += (size_t)FD * FD * 2;
    float* bc   = (float*)w; w += (size_t)FD * 4;
    bf16* alpha = (bf16*)w;  w += (size_t)RR * FD * 2;
    bf16* beta  = (bf16*)w;  w += (size_t)RR * FD * 2;
    bf16* unary = (bf16*)w;  w += (size_t)RR * FD * 2;
    bf16* U2    = (bf16*)w;  w += (size_t)RR * FD * 2;
    float* dpart= (float*)w; w += (size_t)4 * RR * 4;
    float* Mpart= (float*)w; w += (size_t)4 * NB * FD * FD * 4;
    bf16* Qt    = (bf16*)w;  w += (size_t)NB * FD * FD * 2;

    dim3 blk(256);

    prep<<<dim3(2145), blk, 0, stream>>>(x, Wa, Wb, Wu, bu, Wr, xb, Wab, Wbb, Wub, Wrb, Wcb, bc);

    proj4<<<dim3(FD / 64, RR / 128), blk, 0, stream>>>(xb, Wab, Wbb, Wub, Wcb,
                                                       alpha, beta, unary, U2, bu, bc, dpart);

    gemm_tn_mfma<<<dim3(FD / 64, FD / 64, NB * 4), blk, 0, stream>>>(beta, unary, Mpart);

    qt_mfma<<<dim3(FD / 64, FD / 64, NB), blk, 0, stream>>>(Wrb, Mpart, Qt);

    final_mfma<<<dim3(FD / 64, RR / 128), blk, 0, stream>>>(alpha, Qt, dpart, U2, x, out);
}

// Round 4
// 141.083 us; speedup vs baseline: 1.1851x; 1.1851x over previous
//
#include <hip/hip_runtime.h>

// x [B=16, N=1024, F=256] fp32.  Algebra:
//   U2 = x@(Wr@Wu)^T + Wr@bu          (the only "unary" needed)
//   M2t[b][j][k] = sum_i U2[b,i,j] * beta[b,i,k]      (F x F per batch)
//   out[m,j] = (alpha[m,:].M2t[b][j,:] - d[m]*U2[m,j]) / N + x[m,j]
// 4 kernels:
//   K1 prep : Wab,Wbb = bf16(Wa,Wb); Wcb = bf16(Wr@Wu); bc = Wr@bu
//   K2 proj : {alpha,U2} natural bf16 + {betaT,U2T} transposed bf16 + dpart
//   K3 m2   : M2t = U2T @ betaT^T (NT, K=1024, bf16 out)
//   K4 final: out (fp32)

typedef __bf16 bf16;
typedef float floatx4 __attribute__((ext_vector_type(4)));
typedef bf16 bf16x8 __attribute__((ext_vector_type(8)));
typedef bf16 bf16x4 __attribute__((ext_vector_type(4)));

constexpr int FD = 256;
constexpr int NB = 16;
constexpr int NN = 1024;
constexpr int RR = NB * NN;   // 16384

// ---------------- K1: prep (weights only) ----------------
// grid: [0,16) cvt Wa/Wb | [16,80) Wc rows | 80 bc
__global__ __launch_bounds__(256)
void prep(const float* __restrict__ Wa, const float* __restrict__ Wb,
          const float* __restrict__ Wu, const float* __restrict__ bu, const float* __restrict__ Wr,
          bf16* __restrict__ Wab, bf16* __restrict__ Wbb, bf16* __restrict__ Wcb,
          float* __restrict__ bc)
{
    const int blk = blockIdx.x, tid = threadIdx.x;
    if (blk < 16) {  // cvt Wa,Wb: 2 weights x 8 blocks
        int w = blk >> 3, wb = blk & 7;
        const float* src = (w == 0) ? Wa : Wb;
        bf16* dst = (w == 0) ? Wab : Wbb;
        for (int it = 0; it < 8; it++) {
            int i = wb * 8192 + it * 1024 + tid * 4;
            float4 v = *(const float4*)&src[i];
            bf16x4 o = { (bf16)v.x, (bf16)v.y, (bf16)v.z, (bf16)v.w };
            *(bf16x4*)&dst[i] = o;
        }
    } else if (blk < 80) {  // Wc[j][f] = sum_g Wr[j][g]*Wu[g][f], 4 rows/block
        int j0 = (blk - 16) * 4;
        float acc[4] = {};
        for (int g = 0; g < FD; g++) {
            float wu = Wu[g * FD + tid];
            #pragma unroll
            for (int jr = 0; jr < 4; jr++)
                acc[jr] += Wr[(j0 + jr) * FD + g] * wu;
        }
        #pragma unroll
        for (int jr = 0; jr < 4; jr++)
            Wcb[(j0 + jr) * FD + tid] = (bf16)acc[jr];
    } else {  // bc[j] = Wr[j,:].bu
        float s = 0.0f;
        for (int g = 0; g < FD; g++) s += Wr[tid * FD + g] * bu[g];
        bc[tid] = s;
    }
}

// ---------------- K2: proj3 + diag partials + transposed outputs ----------------
// BM=128 rows, BN=64 cols, BK=32; reads x fp32 directly.
__global__ __launch_bounds__(256)
void proj3(const float* __restrict__ x,
           const bf16* __restrict__ W0, const bf16* __restrict__ W1, const bf16* __restrict__ W2,
           bf16* __restrict__ alpha, bf16* __restrict__ U2,
           bf16* __restrict__ betaT, bf16* __restrict__ U2T,
           const float* __restrict__ bc, float* __restrict__ dpart)
{
    constexpr int BM = 128, BN = 64, BK = 32, LDK = 40;
    __shared__ bf16 As[BM][LDK];
    __shared__ bf16 Bs[3][BN][LDK];
    __shared__ bf16 Tr[64][136];
    const int tid = threadIdx.x;
    const int wave = tid >> 6, lane = tid & 63;
    const int q = lane >> 4, l16 = lane & 15;
    const int bm = blockIdx.y * BM, bn = blockIdx.x * BN;
    const bf16* Wp[3] = { W0, W1, W2 };

    floatx4 acc[3][2][4] = {};

    for (int k0 = 0; k0 < FD; k0 += BK) {
        #pragma unroll
        for (int it = 0; it < 2; it++) {  // A: 512 chunks of 8, fp32 -> bf16
            int c = tid + it * 256;
            int row = c >> 2, k8 = (c & 3) * 8;
            const float* src = &x[(size_t)(bm + row) * FD + k0 + k8];
            float4 v0 = *(const float4*)src;
            float4 v1 = *(const float4*)(src + 4);
            bf16x8 o = { (bf16)v0.x, (bf16)v0.y, (bf16)v0.z, (bf16)v0.w,
                         (bf16)v1.x, (bf16)v1.y, (bf16)v1.z, (bf16)v1.w };
            *(bf16x8*)&As[row][k8] = o;
        }
        #pragma unroll
        for (int w = 0; w < 3; w++) {
            int row = tid >> 2, k8 = (tid & 3) * 8;
            *(int4*)&Bs[w][row][k8] = *(const int4*)&Wp[w][(size_t)(bn + row) * FD + k0 + k8];
        }
        __syncthreads();
        bf16x8 af[2];
        #pragma unroll
        for (int mi = 0; mi < 2; mi++)
            af[mi] = *(const bf16x8*)&As[wave * 32 + mi * 16 + l16][q * 8];
        #pragma unroll
        for (int w = 0; w < 3; w++) {
            bf16x8 bq[4];
            #pragma unroll
            for (int nj = 0; nj < 4; nj++)
                bq[nj] = *(const bf16x8*)&Bs[w][nj * 16 + l16][q * 8];
            #pragma unroll
            for (int mi = 0; mi < 2; mi++)
                #pragma unroll
                for (int nj = 0; nj < 4; nj++)
                    acc[w][mi][nj] = __builtin_amdgcn_mfma_f32_16x16x32_bf16(af[mi], bq[nj], acc[w][mi][nj], 0, 0, 0);
        }
        __syncthreads();
    }

    const int b = bm >> 10, n0 = bm & (NN - 1);

    // natural outputs: alpha (w=0), U2 (w=2, +bc)
    #pragma unroll
    for (int mi = 0; mi < 2; mi++)
        #pragma unroll
        for (int i = 0; i < 4; i++) {
            int m = bm + wave * 32 + mi * 16 + q * 4 + i;
            #pragma unroll
            for (int nj = 0; nj < 4; nj++) {
                int n = bn + nj * 16 + l16;
                alpha[(size_t)m * FD + n] = (bf16)acc[0][mi][nj][i];
                U2[(size_t)m * FD + n]    = (bf16)(acc[2][mi][nj][i] + bc[n]);
            }
        }

    // diag partials
    #pragma unroll
    for (int mi = 0; mi < 2; mi++)
        #pragma unroll
        for (int i = 0; i < 4; i++) {
            float p = 0.0f;
            #pragma unroll
            for (int nj = 0; nj < 4; nj++)
                p += acc[0][mi][nj][i] * acc[1][mi][nj][i];
            #pragma unroll
            for (int off = 1; off < 16; off <<= 1) p += __shfl_xor(p, off);
            if (l16 == 0) {
                int m = bm + wave * 32 + mi * 16 + q * 4 + i;
                dpart[(size_t)blockIdx.x * RR + m] = p;
            }
        }

    // transposed outputs: betaT (w=1), U2T (w=2 +bc); via padded LDS
    #pragma unroll
    for (int w = 1; w < 3; w++) {
        __syncthreads();
        #pragma unroll
        for (int mi = 0; mi < 2; mi++)
            #pragma unroll
            for (int i = 0; i < 4; i++)
                #pragma unroll
                for (int nj = 0; nj < 4; nj++) {
                    float v = acc[w][mi][nj][i];
                    if (w == 2) v += bc[bn + nj * 16 + l16];
                    Tr[nj * 16 + l16][wave * 32 + mi * 16 + q * 4 + i] = (bf16)v;
                }
        __syncthreads();
        bf16* dst = ((w == 1) ? betaT : U2T) + (size_t)b * FD * NN;
        int row = tid >> 2;
        #pragma unroll
        for (int it = 0; it < 4; it++) {
            int chunk = (tid & 3) * 4 + it;
            bf16x8 v = *(const bf16x8*)&Tr[row][chunk * 8];
            *(bf16x8*)&dst[(size_t)(bn + row) * NN + n0 + chunk * 8] = v;
        }
    }
}

// ---------------- K3: M2t[b][j][k] = sum_n U2T[b][j][n] * betaT[b][k][n]  (NT, K=1024) ----------------
__global__ __launch_bounds__(256)
void m2_mfma(const bf16* __restrict__ U2T, const bf16* __restrict__ betaT, bf16* __restrict__ M2t)
{
    constexpr int LDK = 40;
    __shared__ bf16 As[64][LDK];
    __shared__ bf16 Bs[64][LDK];
    const int tid = threadIdx.x;
    const int wave = tid >> 6, lane = tid & 63;
    const int q = lane >> 4, l16 = lane & 15;
    const int wj = wave >> 1, wk = wave & 1;
    const int b = blockIdx.z;
    const int bj = blockIdx.y * 64, bk = blockIdx.x * 64;
    const bf16* A = U2T + (size_t)b * FD * NN;
    const bf16* B = betaT + (size_t)b * FD * NN;

    floatx4 acc[2][2] = {};
    for (int n0 = 0; n0 < NN; n0 += 32) {
        int row = tid >> 2, k8 = (tid & 3) * 8;
        *(int4*)&As[row][k8] = *(const int4*)&A[(size_t)(bj + row) * NN + n0 + k8];
        *(int4*)&Bs[row][k8] = *(const int4*)&B[(size_t)(bk + row) * NN + n0 + k8];
        __syncthreads();
        bf16x8 af[2], bq[2];
        #pragma unroll
        for (int mi = 0; mi < 2; mi++)
            af[mi] = *(const bf16x8*)&As[wj * 32 + mi * 16 + l16][q * 8];
        #pragma unroll
        for (int kj = 0; kj < 2; kj++)
            bq[kj] = *(const bf16x8*)&Bs[wk * 32 + kj * 16 + l16][q * 8];
        #pragma unroll
        for (int mi = 0; mi < 2; mi++)
            #pragma unroll
            for (int kj = 0; kj < 2; kj++)
                acc[mi][kj] = __builtin_amdgcn_mfma_f32_16x16x32_bf16(af[mi], bq[kj], acc[mi][kj], 0, 0, 0);
        __syncthreads();
    }
    bf16* Mb = M2t + (size_t)b * FD * FD;
    #pragma unroll
    for (int mi = 0; mi < 2; mi++)
        #pragma unroll
        for (int i = 0; i < 4; i++) {
            int j = bj + wj * 32 + mi * 16 + q * 4 + i;
            #pragma unroll
            for (int kj = 0; kj < 2; kj++)
                Mb[(size_t)j * FD + bk + wk * 32 + kj * 16 + l16] = (bf16)acc[mi][kj][i];
        }
}

// ---------------- K4: out = (alpha @ M2t[b]^(NT) - d*U2)/N + x ----------------
__global__ __launch_bounds__(256)
void final_mfma(const bf16* __restrict__ alpha, const bf16* __restrict__ M2t,
                const float* __restrict__ dpart, const bf16* __restrict__ U2,
                const float* __restrict__ x, float* __restrict__ out)
{
    constexpr int BM = 128, BN = 64, BK = 32, LDK = 40;
    __shared__ bf16 As[BM][LDK];
    __shared__ bf16 Bs[BN][LDK];
    const int tid = threadIdx.x;
    const int wave = tid >> 6, lane = tid & 63;
    const int q = lane >> 4, l16 = lane & 15;
    const int bm = blockIdx.y * BM, bn = blockIdx.x * BN;
    const bf16* Qb = M2t + (size_t)(bm >> 10) * FD * FD;

    floatx4 acc[2][4] = {};
    for (int k0 = 0; k0 < FD; k0 += BK) {
        int c = tid, row = c >> 2, k8 = (c & 3) * 8;
        *(int4*)&As[row][k8] = *(const int4*)&alpha[(size_t)(bm + row) * FD + k0 + k8];
        c = tid + 256; row = c >> 2; k8 = (c & 3) * 8;
        *(int4*)&As[row][k8] = *(const int4*)&alpha[(size_t)(bm + row) * FD + k0 + k8];
        int rb = tid >> 2, kb8 = (tid & 3) * 8;
        *(int4*)&Bs[rb][kb8] = *(const int4*)&Qb[(size_t)(bn + rb) * FD + k0 + kb8];
        __syncthreads();
        bf16x8 af[2], bq[4];
        #pragma unroll
        for (int mi = 0; mi < 2; mi++)
            af[mi] = *(const bf16x8*)&As[wave * 32 + mi * 16 + l16][q * 8];
        #pragma unroll
        for (int nj = 0; nj < 4; nj++)
            bq[nj] = *(const bf16x8*)&Bs[nj * 16 + l16][q * 8];
        #pragma unroll
        for (int mi = 0; mi < 2; mi++)
            #pragma unroll
            for (int nj = 0; nj < 4; nj++)
                acc[mi][nj] = __builtin_amdgcn_mfma_f32_16x16x32_bf16(af[mi], bq[nj], acc[mi][nj], 0, 0, 0);
        __syncthreads();
    }

    #pragma unroll
    for (int mi = 0; mi < 2; mi++)
        #pragma unroll
        for (int i = 0; i < 4; i++) {
            int m = bm + wave * 32 + mi * 16 + q * 4 + i;
            float d = dpart[m] + dpart[RR + m] + dpart[2 * RR + m] + dpart[3 * RR + m];
            #pragma unroll
            for (int nj = 0; nj < 4; nj++) {
                int n = bn + nj * 16 + l16;
                float v = (acc[mi][nj][i] - d * (float)U2[(size_t)m * FD + n]) * (1.0f / 1024.0f);
                out[(size_t)m * FD + n] = v + x[(size_t)m * FD + n];
            }
        }
}

extern "C" void kernel_launch(void* const* d_in, const int* in_sizes, int n_in,
                              void* d_out, int out_size, void* d_ws, size_t ws_size,
                              hipStream_t stream)
{
    const float* x  = (const float*)d_in[0];
    const float* Wa = (const float*)d_in[1];
    const float* Wb = (const float*)d_in[2];
    const float* Wu = (const float*)d_in[3];
    const float* bu = (const float*)d_in[4];
    const float* Wr = (const float*)d_in[5];
    float* out = (float*)d_out;

    char* w = (char*)d_ws;
    bf16* Wab   = (bf16*)w;  w += (size_t)FD * FD * 2;
    bf16* Wbb   = (bf16*)w;  w += (size_t)FD * FD * 2;
    bf16* Wcb   = (bf16*)w;  w += (size_t)FD * FD * 2;
    float* bc   = (float*)w; w += (size_t)FD * 4;
    bf16* alpha = (bf16*)w;  w += (size_t)RR * FD * 2;   // 8 MB
    bf16* U2    = (bf16*)w;  w += (size_t)RR * FD * 2;   // 8 MB
    bf16* betaT = (bf16*)w;  w += (size_t)RR * FD * 2;   // 8 MB  [b][f][n]
    bf16* U2T   = (bf16*)w;  w += (size_t)RR * FD * 2;   // 8 MB  [b][f][n]
    bf16* M2t   = (bf16*)w;  w += (size_t)NB * FD * FD * 2;  // 2 MB
    float* dpart= (float*)w; w += (size_t)4 * RR * 4;

    dim3 blk(256);

    prep<<<dim3(81), blk, 0, stream>>>(Wa, Wb, Wu, bu, Wr, Wab, Wbb, Wcb, bc);

    proj3<<<dim3(FD / 64, RR / 128), blk, 0, stream>>>(x, Wab, Wbb, Wcb,
                                                       alpha, U2, betaT, U2T, bc, dpart);

    m2_mfma<<<dim3(FD / 64, FD / 64, NB), blk, 0, stream>>>(U2T, betaT, M2t);

    final_mfma<<<dim3(FD / 64, RR / 128), blk, 0, stream>>>(alpha, M2t, dpart, U2, x, out);
}

// Round 5
// 127.845 us; speedup vs baseline: 1.3078x; 1.1035x over previous
//
#include <hip/hip_runtime.h>

// x [B=16, N=1024, F=256] fp32.  Algebra:
//   U2 = x@(Wr@Wu)^T + Wr@bu
//   M2t[b][j][k] = sum_i U2[b,i,j] * beta[b,i,k]      (F x F per batch)
//   out[m,j] = (alpha[m,:].M2t[b][j,:] - d[m]*U2[m,j]) / N + x[m,j]
// K1 prep : Wcb = bf16(Wr@Wu); bc = Wr@bu           (Wa/Wb converted inline in proj3)
// K2 proj3: {alpha,U2} natural + {betaT,U2T} transposed + dpart; packed b128 stores
// K3 m2   : M2t = U2T @ betaT^T (NT, K=1024), packed stores
// K4 final: out fp32

typedef __bf16 bf16;
typedef float floatx4 __attribute__((ext_vector_type(4)));
typedef bf16 bf16x8 __attribute__((ext_vector_type(8)));
typedef bf16 bf16x4 __attribute__((ext_vector_type(4)));

constexpr int FD = 256;
constexpr int NB = 16;
constexpr int NN = 1024;
constexpr int RR = NB * NN;   // 16384

__device__ __forceinline__ bf16x8 cvt8(float4 a, float4 b) {
    bf16x8 o = { (bf16)a.x, (bf16)a.y, (bf16)a.z, (bf16)a.w,
                 (bf16)b.x, (bf16)b.y, (bf16)b.z, (bf16)b.w };
    return o;
}

// ---------------- K1: prep ----------------
__global__ __launch_bounds__(256)
void prep(const float* __restrict__ Wu, const float* __restrict__ bu, const float* __restrict__ Wr,
          bf16* __restrict__ Wcb, float* __restrict__ bc)
{
    const int blk = blockIdx.x, tid = threadIdx.x;
    if (blk < 256) {  // Wc[j][f] = sum_g Wr[j][g]*Wu[g][f]; one j per block
        const int j = blk;
        float acc = 0.0f;
        for (int g = 0; g < FD; g += 4) {
            float4 wr = *(const float4*)&Wr[j * FD + g];
            acc += wr.x * Wu[g * FD + tid] + wr.y * Wu[(g + 1) * FD + tid]
                 + wr.z * Wu[(g + 2) * FD + tid] + wr.w * Wu[(g + 3) * FD + tid];
        }
        Wcb[j * FD + tid] = (bf16)acc;
    } else {  // bc[j] = Wr[j,:].bu
        float s = 0.0f;
        for (int g = 0; g < FD; g++) s += Wr[tid * FD + g] * bu[g];
        bc[tid] = s;
    }
}

// ---------------- K2: proj3 ----------------
__global__ __launch_bounds__(256)
void proj3(const float* __restrict__ x,
           const float* __restrict__ Wa, const float* __restrict__ Wb, const bf16* __restrict__ Wc,
           bf16* __restrict__ alpha, bf16* __restrict__ U2,
           bf16* __restrict__ betaT, bf16* __restrict__ U2T,
           const float* __restrict__ bc, float* __restrict__ dpart)
{
    constexpr int BM = 128, BN = 64, BK = 32, LDK = 36;
    __shared__ bf16 As[BM][LDK];
    __shared__ bf16 Bs[3][BN][LDK];
    __shared__ bf16 Tr[8960];   // union: natural [128][68] (8704) / transposed [64][140] (8960)
    const int tid = threadIdx.x;
    const int wave = tid >> 6, lane = tid & 63;
    const int q = lane >> 4, l16 = lane & 15;
    const int bm = blockIdx.y * BM, bn = blockIdx.x * BN;

    // staging thread->element mapping
    const int rowA0 = tid >> 2,          k8A0 = (tid & 3) * 8;
    const int rowA1 = (tid + 256) >> 2,  k8A1 = (tid & 3) * 8;
    const int rowW  = tid >> 2,          k8W  = (tid & 3) * 8;

    bf16x8 pxa0, pxa1, pwa, pwb; int4 pwc;
#define PROJ_LOAD(KK) do { \
        const float* s0 = &x[(size_t)(bm + rowA0) * FD + (KK) + k8A0]; \
        pxa0 = cvt8(*(const float4*)s0, *(const float4*)(s0 + 4)); \
        const float* s1 = &x[(size_t)(bm + rowA1) * FD + (KK) + k8A1]; \
        pxa1 = cvt8(*(const float4*)s1, *(const float4*)(s1 + 4)); \
        const float* sa = &Wa[(size_t)(bn + rowW) * FD + (KK) + k8W]; \
        pwa = cvt8(*(const float4*)sa, *(const float4*)(sa + 4)); \
        const float* sb = &Wb[(size_t)(bn + rowW) * FD + (KK) + k8W]; \
        pwb = cvt8(*(const float4*)sb, *(const float4*)(sb + 4)); \
        pwc = *(const int4*)&Wc[(size_t)(bn + rowW) * FD + (KK) + k8W]; \
    } while (0)

    floatx4 acc[3][2][4] = {};
    PROJ_LOAD(0);

    for (int k0 = 0; k0 < FD; k0 += BK) {
        *(bf16x8*)&As[rowA0][k8A0] = pxa0;
        *(bf16x8*)&As[rowA1][k8A1] = pxa1;
        *(bf16x8*)&Bs[0][rowW][k8W] = pwa;
        *(bf16x8*)&Bs[1][rowW][k8W] = pwb;
        *(int4*)&Bs[2][rowW][k8W] = pwc;
        __syncthreads();
        if (k0 + BK < FD) PROJ_LOAD(k0 + BK);
        bf16x8 af[2];
        #pragma unroll
        for (int mi = 0; mi < 2; mi++)
            af[mi] = *(const bf16x8*)&As[wave * 32 + mi * 16 + l16][q * 8];
        #pragma unroll
        for (int w = 0; w < 3; w++) {
            bf16x8 bq[4];
            #pragma unroll
            for (int nj = 0; nj < 4; nj++)
                bq[nj] = *(const bf16x8*)&Bs[w][nj * 16 + l16][q * 8];
            #pragma unroll
            for (int mi = 0; mi < 2; mi++)
                #pragma unroll
                for (int nj = 0; nj < 4; nj++)
                    acc[w][mi][nj] = __builtin_amdgcn_mfma_f32_16x16x32_bf16(af[mi], bq[nj], acc[w][mi][nj], 0, 0, 0);
        }
        __syncthreads();
    }
#undef PROJ_LOAD

    const int b = bm >> 10, n0 = bm & (NN - 1);
    float bcv[4];
    #pragma unroll
    for (int nj = 0; nj < 4; nj++) bcv[nj] = bc[bn + nj * 16 + l16];

    // diag partials
    #pragma unroll
    for (int mi = 0; mi < 2; mi++)
        #pragma unroll
        for (int i = 0; i < 4; i++) {
            float p = 0.0f;
            #pragma unroll
            for (int nj = 0; nj < 4; nj++)
                p += acc[0][mi][nj][i] * acc[1][mi][nj][i];
            #pragma unroll
            for (int off = 1; off < 16; off <<= 1) p += __shfl_xor(p, off);
            if (l16 == 0) {
                int m = bm + wave * 32 + mi * 16 + q * 4 + i;
                dpart[(size_t)blockIdx.x * RR + m] = p;
            }
        }

    // natural outputs via [128][68] repack: alpha (w=0), U2 (w=2 +bc)
    #pragma unroll
    for (int pass = 0; pass < 2; pass++) {
        const int w = pass ? 2 : 0;
        __syncthreads();
        #pragma unroll
        for (int mi = 0; mi < 2; mi++)
            #pragma unroll
            for (int i = 0; i < 4; i++) {
                int ml = wave * 32 + mi * 16 + q * 4 + i;
                #pragma unroll
                for (int nj = 0; nj < 4; nj++) {
                    float v = acc[w][mi][nj][i];
                    if (w == 2) v += bcv[nj];
                    Tr[ml * 68 + nj * 16 + l16] = (bf16)v;
                }
            }
        __syncthreads();
        bf16* dst = pass ? U2 : alpha;
        #pragma unroll
        for (int it = 0; it < 4; it++) {
            int c = tid + it * 256;
            int row = c >> 3, chunk = c & 7;
            bf16x8 v = *(const bf16x8*)&Tr[row * 68 + chunk * 8];
            *(bf16x8*)&dst[(size_t)(bm + row) * FD + bn + chunk * 8] = v;
        }
    }

    // transposed outputs via [64][140] repack: betaT (w=1), U2T (w=2 +bc)
    #pragma unroll
    for (int pass = 0; pass < 2; pass++) {
        const int w = pass ? 2 : 1;
        __syncthreads();
        #pragma unroll
        for (int mi = 0; mi < 2; mi++)
            #pragma unroll
            for (int nj = 0; nj < 4; nj++) {
                bf16x4 v4;
                #pragma unroll
                for (int i = 0; i < 4; i++) {
                    float v = acc[w][mi][nj][i];
                    if (w == 2) v += bcv[nj];
                    v4[i] = (bf16)v;
                }
                *(bf16x4*)&Tr[(nj * 16 + l16) * 140 + wave * 32 + mi * 16 + q * 4] = v4;
            }
        __syncthreads();
        bf16* dst = (pass ? U2T : betaT) + (size_t)b * FD * NN;
        #pragma unroll
        for (int it = 0; it < 4; it++) {
            int c = tid + it * 256;
            int row = c >> 4, chunk = c & 15;
            bf16x8 v = *(const bf16x8*)&Tr[row * 140 + chunk * 8];
            *(bf16x8*)&dst[(size_t)(bn + row) * NN + n0 + chunk * 8] = v;
        }
    }
}

// ---------------- K3: M2t[b][j][k] = sum_n U2T[b][j][n] * betaT[b][k][n] ----------------
__global__ __launch_bounds__(256)
void m2_mfma(const bf16* __restrict__ U2T, const bf16* __restrict__ betaT, bf16* __restrict__ M2t)
{
    constexpr int LDK = 36;
    __shared__ bf16 As[64][LDK];
    __shared__ bf16 Bs[64][LDK];
    __shared__ bf16 Tr[64 * 68];
    const int tid = threadIdx.x;
    const int wave = tid >> 6, lane = tid & 63;
    const int q = lane >> 4, l16 = lane & 15;
    const int wj = wave >> 1, wk = wave & 1;
    const int b = blockIdx.z;
    const int bj = blockIdx.y * 64, bk = blockIdx.x * 64;
    const int row = tid >> 2, k8 = (tid & 3) * 8;
    const bf16* Arow = U2T + (size_t)b * FD * NN + (size_t)(bj + row) * NN + k8;
    const bf16* Brow = betaT + (size_t)b * FD * NN + (size_t)(bk + row) * NN + k8;

    int4 ra = *(const int4*)&Arow[0];
    int4 rb = *(const int4*)&Brow[0];
    floatx4 acc[2][2] = {};
    for (int n0 = 0; n0 < NN; n0 += 32) {
        *(int4*)&As[row][k8] = ra;
        *(int4*)&Bs[row][k8] = rb;
        __syncthreads();
        if (n0 + 32 < NN) { ra = *(const int4*)&Arow[n0 + 32]; rb = *(const int4*)&Brow[n0 + 32]; }
        bf16x8 af[2], bq[2];
        #pragma unroll
        for (int mi = 0; mi < 2; mi++)
            af[mi] = *(const bf16x8*)&As[wj * 32 + mi * 16 + l16][q * 8];
        #pragma unroll
        for (int kj = 0; kj < 2; kj++)
            bq[kj] = *(const bf16x8*)&Bs[wk * 32 + kj * 16 + l16][q * 8];
        #pragma unroll
        for (int mi = 0; mi < 2; mi++)
            #pragma unroll
            for (int kj = 0; kj < 2; kj++)
                acc[mi][kj] = __builtin_amdgcn_mfma_f32_16x16x32_bf16(af[mi], bq[kj], acc[mi][kj], 0, 0, 0);
        __syncthreads();
    }
    // repack [64][68] then b128 stores
    __syncthreads();
    #pragma unroll
    for (int mi = 0; mi < 2; mi++)
        #pragma unroll
        for (int i = 0; i < 4; i++) {
            int jl = wj * 32 + mi * 16 + q * 4 + i;
            #pragma unroll
            for (int kj = 0; kj < 2; kj++)
                Tr[jl * 68 + wk * 32 + kj * 16 + l16] = (bf16)acc[mi][kj][i];
        }
    __syncthreads();
    bf16* Mb = M2t + (size_t)b * FD * FD;
    #pragma unroll
    for (int it = 0; it < 2; it++) {
        int c = tid + it * 256;
        int r = c >> 3, chunk = c & 7;
        bf16x8 v = *(const bf16x8*)&Tr[r * 68 + chunk * 8];
        *(bf16x8*)&Mb[(size_t)(bj + r) * FD + bk + chunk * 8] = v;
    }
}

// ---------------- K4: out = (alpha @ M2t[b]^T(NT) - d*U2)/N + x ----------------
__global__ __launch_bounds__(256)
void final_mfma(const bf16* __restrict__ alpha, const bf16* __restrict__ M2t,
                const float* __restrict__ dpart, const bf16* __restrict__ U2,
                const float* __restrict__ x, float* __restrict__ out)
{
    constexpr int BM = 128, BN = 64, BK = 32, LDK = 36;
    __shared__ bf16 As[BM][LDK];
    __shared__ bf16 Bs[BN][LDK];
    const int tid = threadIdx.x;
    const int wave = tid >> 6, lane = tid & 63;
    const int q = lane >> 4, l16 = lane & 15;
    const int bm = blockIdx.y * BM, bn = blockIdx.x * BN;
    const bf16* Qb = M2t + (size_t)(bm >> 10) * FD * FD;

    const int rowA0 = tid >> 2,         k8A0 = (tid & 3) * 8;
    const int rowA1 = (tid + 256) >> 2, k8A1 = (tid & 3) * 8;
    const int rowB  = tid >> 2,         k8B  = (tid & 3) * 8;

    int4 ra0 = *(const int4*)&alpha[(size_t)(bm + rowA0) * FD + k8A0];
    int4 ra1 = *(const int4*)&alpha[(size_t)(bm + rowA1) * FD + k8A1];
    int4 rb  = *(const int4*)&Qb[(size_t)(bn + rowB) * FD + k8B];

    floatx4 acc[2][4] = {};
    for (int k0 = 0; k0 < FD; k0 += BK) {
        *(int4*)&As[rowA0][k8A0] = ra0;
        *(int4*)&As[rowA1][k8A1] = ra1;
        *(int4*)&Bs[rowB][k8B] = rb;
        __syncthreads();
        if (k0 + BK < FD) {
            ra0 = *(const int4*)&alpha[(size_t)(bm + rowA0) * FD + k0 + BK + k8A0];
            ra1 = *(const int4*)&alpha[(size_t)(bm + rowA1) * FD + k0 + BK + k8A1];
            rb  = *(const int4*)&Qb[(size_t)(bn + rowB) * FD + k0 + BK + k8B];
        }
        bf16x8 af[2], bq[4];
        #pragma unroll
        for (int mi = 0; mi < 2; mi++)
            af[mi] = *(const bf16x8*)&As[wave * 32 + mi * 16 + l16][q * 8];
        #pragma unroll
        for (int nj = 0; nj < 4; nj++)
            bq[nj] = *(const bf16x8*)&Bs[nj * 16 + l16][q * 8];
        #pragma unroll
        for (int mi = 0; mi < 2; mi++)
            #pragma unroll
            for (int nj = 0; nj < 4; nj++)
                acc[mi][nj] = __builtin_amdgcn_mfma_f32_16x16x32_bf16(af[mi], bq[nj], acc[mi][nj], 0, 0, 0);
        __syncthreads();
    }

    #pragma unroll
    for (int mi = 0; mi < 2; mi++)
        #pragma unroll
        for (int i = 0; i < 4; i++) {
            int m = bm + wave * 32 + mi * 16 + q * 4 + i;
            float d = dpart[m] + dpart[RR + m] + dpart[2 * RR + m] + dpart[3 * RR + m];
            #pragma unroll
            for (int nj = 0; nj < 4; nj++) {
                int n = bn + nj * 16 + l16;
                float v = (acc[mi][nj][i] - d * (float)U2[(size_t)m * FD + n]) * (1.0f / 1024.0f);
                out[(size_t)m * FD + n] = v + x[(size_t)m * FD + n];
            }
        }
}

extern "C" void kernel_launch(void* const* d_in, const int* in_sizes, int n_in,
                              void* d_out, int out_size, void* d_ws, size_t ws_size,
                              hipStream_t stream)
{
    const float* x  = (const float*)d_in[0];
    const float* Wa = (const float*)d_in[1];
    const float* Wb = (const float*)d_in[2];
    const float* Wu = (const float*)d_in[3];
    const float* bu = (const float*)d_in[4];
    const float* Wr = (const float*)d_in[5];
    float* out = (float*)d_out;

    char* w = (char*)d_ws;
    bf16* Wcb   = (bf16*)w;  w += (size_t)FD * FD * 2;
    float* bc   = (float*)w; w += (size_t)FD * 4;
    bf16* alpha = (bf16*)w;  w += (size_t)RR * FD * 2;
    bf16* U2    = (bf16*)w;  w += (size_t)RR * FD * 2;
    bf16* betaT = (bf16*)w;  w += (size_t)RR * FD * 2;
    bf16* U2T   = (bf16*)w;  w += (size_t)RR * FD * 2;
    bf16* M2t   = (bf16*)w;  w += (size_t)NB * FD * FD * 2;
    float* dpart= (float*)w; w += (size_t)4 * RR * 4;

    dim3 blk(256);

    prep<<<dim3(257), blk, 0, stream>>>(Wu, bu, Wr, Wcb, bc);

    proj3<<<dim3(FD / 64, RR / 128), blk, 0, stream>>>(x, Wa, Wb, Wcb,
                                                       alpha, U2, betaT, U2T, bc, dpart);

    m2_mfma<<<dim3(FD / 64, FD / 64, NB), blk, 0, stream>>>(U2T, betaT, M2t);

    final_mfma<<<dim3(FD / 64, RR / 128), blk, 0, stream>>>(alpha, M2t, dpart, U2, x, out);
}